// Round 1
// baseline (503.649 us; speedup 1.0000x reference)
//
#include <hip/hip_runtime.h>
#include <hip/hip_bf16.h>

typedef __hip_bfloat16 bf16;
typedef unsigned short ush;
typedef __attribute__((ext_vector_type(8))) unsigned short ush8;
typedef __attribute__((ext_vector_type(4))) float f4;

#define IN_CH 32
#define HID 128
#define OUT_CH 32
#define S_CAP 32             // fixed csr slots per node; rank>=S_CAP -> overflow list
#define OVF_CAP 100000       // overflow pair capacity (bench data: ~0 used; Poisson(16) tail tiny)

__device__ __forceinline__ float bf2f(ush u) {
    return __uint_as_float(((unsigned)u) << 16);
}
__device__ __forceinline__ ush f2bf(float f) {
    __hip_bfloat16 b = __float2bfloat16(f);
    return __builtin_bit_cast(ush, b);
}
__device__ __forceinline__ float ldf(const void* __restrict__ p, size_t idx, int isbf16) {
    return isbf16 ? bf2f(((const ush*)p)[idx]) : ((const float*)p)[idx];
}
__device__ __forceinline__ int ld_edge(const int* __restrict__ ei, size_t elem, int wide) {
    return wide ? ei[2 * elem] : ei[elem];
}

// ---------- sniff dtypes: flags[0]=float_is_bf16, flags[1]=edge_is_i64 ----------
__global__ void k_detect(const unsigned short* __restrict__ xraw,
                         const int* __restrict__ ei, int* __restrict__ flags) {
    __shared__ int cnt_exp, any_nz;
    if (threadIdx.x == 0) { cnt_exp = 0; any_nz = 0; }
    __syncthreads();
    int local = 0;
    for (int k = threadIdx.x; k < 4096; k += 256) {
        int e = (xraw[k] >> 7) & 0xFF;
        if (e >= 100 && e <= 140) ++local;
    }
    atomicAdd(&cnt_exp, local);
    for (int k = threadIdx.x; k < 2048; k += 256)
        if (ei[2 * k + 1] != 0) any_nz = 1;   // benign race
    __syncthreads();
    if (threadIdx.x == 0) {
        flags[0] = (cnt_exp > 3500) ? 1 : 0;
        flags[1] = any_nz ? 0 : 1;
    }
}

// ---------- fused count+place: ONE atomic per edge ----------
__global__ void k_fillp(const int* __restrict__ ei, int n_edges,
                        const int* __restrict__ flags,
                        int* __restrict__ cnt, int* __restrict__ csr,
                        int* __restrict__ ovf, int* __restrict__ ovfn) {
    int e = blockIdx.x * blockDim.x + threadIdx.x;
    if (e >= n_edges) return;
    int w = flags[1];
    int d  = ld_edge(ei, (size_t)n_edges + e, w);
    int sc = ld_edge(ei, (size_t)e, w);
    int r = atomicAdd(&cnt[d], 1);
    if (r < S_CAP) {
        csr[d * S_CAP + r] = sc;
    } else {
        int o = atomicAdd(ovfn, 1);
        if (o < OVF_CAP) { ((int2*)ovf)[o] = make_int2(d, sc); }
    }
}

// ==== layer 1: h[i] = relu(mean_j x[j] @ W1l^T + x[i] @ W1r^T + b1), 32 -> 128 ====
// wave-per-node; lane = (slot 0..15 = edge slot, chunk 0..3 = 8-channel chunk)
__global__ __launch_bounds__(256) void k_l1(
        const void* __restrict__ x,
        const int* __restrict__ cnt, const int* __restrict__ csr,
        const int* __restrict__ ovf, const int* __restrict__ ovfn,
        const void* __restrict__ W1l, const void* __restrict__ W1r,
        const void* __restrict__ b1,
        const int* __restrict__ flags,
        ush* __restrict__ hout, int n_nodes) {
    __shared__ ush wst[2 * HID * IN_CH];   // 16 KB: W1l then W1r, bf16 [o][c]
    int fb = flags[0];
    int t = threadIdx.x;
    for (int idx = t; idx < HID * IN_CH; idx += 256) {
        wst[idx]                 = f2bf(ldf(W1l, idx, fb));
        wst[HID * IN_CH + idx]   = f2bf(ldf(W1r, idx, fb));
    }
    __syncthreads();
    int wave = t >> 6, lane = t & 63;
    int slot = lane >> 2;    // 0..15
    int chunk = lane & 3;    // 0..3
    ush8 wlr[8], wrr[8];
    float bsr[8];
#pragma unroll
    for (int j = 0; j < 8; ++j) {
        int o = slot * 8 + j;
        wlr[j] = *(const ush8*)&wst[o * IN_CH + chunk * 8];
        wrr[j] = *(const ush8*)&wst[HID * IN_CH + o * IN_CH + chunk * 8];
        bsr[j] = ldf(b1, o, fb);
    }
    int gw = blockIdx.x * 4 + wave;
    int nw = gridDim.x * 4;
    for (int i = gw; i < n_nodes; i += nw) {
        int dg = cnt[i];
        int lim = min(dg, S_CAP);
        int idxv = csr[i * S_CAP + lane];   // lanes >= lim read slack; never used
        float acc[8] = {0, 0, 0, 0, 0, 0, 0, 0};
        float sv[8];
        if (fb) {
            const ush* xb = (const ush*)x;
            for (int g = 0; g < lim; g += 16) {
                int k = g + slot;
                int src = __shfl(idxv, k);
                bool ok = k < lim;
                ush8 v = *(const ush8*)(xb + (size_t)(ok ? src : i) * IN_CH + chunk * 8);
#pragma unroll
                for (int j = 0; j < 8; ++j) acc[j] += ok ? bf2f(v[j]) : 0.0f;
            }
            if (dg > S_CAP) {   // wave-uniform; ~never taken on bench data
                int on = min(*ovfn, OVF_CAP);
                for (int k = 0; k < on; ++k) {
                    int2 pr = ((const int2*)ovf)[k];
                    if (pr.x == i && slot == 0) {
                        ush8 v = *(const ush8*)(xb + (size_t)pr.y * IN_CH + chunk * 8);
#pragma unroll
                        for (int j = 0; j < 8; ++j) acc[j] += bf2f(v[j]);
                    }
                }
            }
            ush8 svv = *(const ush8*)(xb + (size_t)i * IN_CH + chunk * 8);
#pragma unroll
            for (int j = 0; j < 8; ++j) sv[j] = bf2f(svv[j]);
        } else {
            const float* xb = (const float*)x;
            for (int g = 0; g < lim; g += 16) {
                int k = g + slot;
                int src = __shfl(idxv, k);
                bool ok = k < lim;
                const float* rp = xb + (size_t)(ok ? src : i) * IN_CH + chunk * 8;
                f4 a0 = *(const f4*)rp;
                f4 a1 = *(const f4*)(rp + 4);
#pragma unroll
                for (int j = 0; j < 4; ++j) {
                    acc[j]     += ok ? a0[j] : 0.0f;
                    acc[4 + j] += ok ? a1[j] : 0.0f;
                }
            }
            if (dg > S_CAP) {
                int on = min(*ovfn, OVF_CAP);
                for (int k = 0; k < on; ++k) {
                    int2 pr = ((const int2*)ovf)[k];
                    if (pr.x == i && slot == 0) {
                        const float* rp = xb + (size_t)pr.y * IN_CH + chunk * 8;
                        f4 a0 = *(const f4*)rp;
                        f4 a1 = *(const f4*)(rp + 4);
#pragma unroll
                        for (int j = 0; j < 4; ++j) { acc[j] += a0[j]; acc[4 + j] += a1[j]; }
                    }
                }
            }
            const float* rp = xb + (size_t)i * IN_CH + chunk * 8;
            f4 a0 = *(const f4*)rp;
            f4 a1 = *(const f4*)(rp + 4);
#pragma unroll
            for (int j = 0; j < 4; ++j) { sv[j] = a0[j]; sv[4 + j] = a1[j]; }
        }
#pragma unroll
        for (int j = 0; j < 8; ++j) {
            acc[j] += __shfl_xor(acc[j], 4);
            acc[j] += __shfl_xor(acc[j], 8);
            acc[j] += __shfl_xor(acc[j], 16);
            acc[j] += __shfl_xor(acc[j], 32);
        }
        float rdeg = 1.0f / (float)(dg > 1 ? dg : 1);
#pragma unroll
        for (int j = 0; j < 8; ++j) acc[j] *= rdeg;
        float po[8];
#pragma unroll
        for (int j = 0; j < 8; ++j) {
            float s = 0.0f;
#pragma unroll
            for (int c = 0; c < 8; ++c)
                s += acc[c] * bf2f(wlr[j][c]) + sv[c] * bf2f(wrr[j][c]);
            po[j] = s;
        }
#pragma unroll
        for (int j = 0; j < 8; ++j) {
            po[j] += __shfl_xor(po[j], 1);
            po[j] += __shfl_xor(po[j], 2);
        }
        if (chunk == 0) {
            ush8 ov;
#pragma unroll
            for (int j = 0; j < 8; ++j) {
                float v = po[j] + bsr[j];
                ov[j] = f2bf(v > 0.0f ? v : 0.0f);
            }
            *(ush8*)(hout + (size_t)i * HID + slot * 8) = ov;
        }
    }
}

// ==== k_g: g -> DENSE gbuf[N][32] (64B rows, gather-friendly); s -> h row [32..63] ====
// wave-per-node; lane = (slot 0..3 = 8-output group, chunk 0..15 = 8-ch chunk)
__global__ __launch_bounds__(256) void k_g(
        ush* __restrict__ h, ush* __restrict__ gout,
        const void* __restrict__ W2l, const void* __restrict__ W2r,
        const void* __restrict__ b2,
        const int* __restrict__ flags, int n_nodes) {
    __shared__ ush wst[2 * OUT_CH * HID];  // 16 KB
    int fb = flags[0];
    int t = threadIdx.x;
    for (int idx = t; idx < OUT_CH * HID; idx += 256) {
        wst[idx]                  = f2bf(ldf(W2l, idx, fb));
        wst[OUT_CH * HID + idx]   = f2bf(ldf(W2r, idx, fb));
    }
    __syncthreads();
    int wave = t >> 6, lane = t & 63;
    int slot = lane >> 4;    // 0..3
    int chunk = lane & 15;   // 0..15
    ush8 wlr[8], wrr[8];
    float bsr[8];
#pragma unroll
    for (int j = 0; j < 8; ++j) {
        int o = slot * 8 + j;
        wlr[j] = *(const ush8*)&wst[o * HID + chunk * 8];
        wrr[j] = *(const ush8*)&wst[OUT_CH * HID + o * HID + chunk * 8];
        bsr[j] = ldf(b2, o, fb);
    }
    int gw = blockIdx.x * 4 + wave;
    int nw = gridDim.x * 4;
    for (int i = gw; i < n_nodes; i += nw) {
        ush8 hv = *(const ush8*)(h + (size_t)i * HID + chunk * 8);  // read BEFORE write
        float sv[8];
#pragma unroll
        for (int j = 0; j < 8; ++j) sv[j] = bf2f(hv[j]);
        float pg[8], ps[8];
#pragma unroll
        for (int j = 0; j < 8; ++j) {
            float a = 0.0f, b = 0.0f;
#pragma unroll
            for (int c = 0; c < 8; ++c) {
                a += sv[c] * bf2f(wlr[j][c]);
                b += sv[c] * bf2f(wrr[j][c]);
            }
            pg[j] = a; ps[j] = b;
        }
#pragma unroll
        for (int j = 0; j < 8; ++j) {
            pg[j] += __shfl_xor(pg[j], 1);
            pg[j] += __shfl_xor(pg[j], 2);
            pg[j] += __shfl_xor(pg[j], 4);
            pg[j] += __shfl_xor(pg[j], 8);
            ps[j] += __shfl_xor(ps[j], 1);
            ps[j] += __shfl_xor(ps[j], 2);
            ps[j] += __shfl_xor(ps[j], 4);
            ps[j] += __shfl_xor(ps[j], 8);
        }
        if (chunk == 0) {
            ush8 go, so;
#pragma unroll
            for (int j = 0; j < 8; ++j) {
                go[j] = f2bf(pg[j]);
                so[j] = f2bf(ps[j] + bsr[j]);
            }
            *(ush8*)(gout + (size_t)i * OUT_CH + slot * 8)    = go;   // g -> dense [N][32]
            *(ush8*)(h + (size_t)i * HID + 32 + slot * 8)     = so;   // s -> h row [32..63]
        }
    }
}

// ==== out[i] = mean_j g[j] + s[i] — dense 64B-row gather from gbuf ====
// wave-per-node; lane = (slot 0..15 = edge slot, chunk 0..3 = 8-channel chunk)
__global__ __launch_bounds__(256) void k_l2g(
        const ush* __restrict__ gbuf, const ush* __restrict__ hs,
        const int* __restrict__ cnt, const int* __restrict__ csr,
        const int* __restrict__ ovf, const int* __restrict__ ovfn,
        const int* __restrict__ flags,
        void* __restrict__ out, int n_nodes) {
    int fb = flags[0];
    int t = threadIdx.x;
    int wave = t >> 6, lane = t & 63;
    int slot = lane >> 2;    // 0..15
    int chunk = lane & 3;    // 0..3
    int gw = blockIdx.x * 4 + wave;
    int nw = gridDim.x * 4;
    for (int i = gw; i < n_nodes; i += nw) {
        int dg = cnt[i];
        int lim = min(dg, S_CAP);
        int idxv = csr[i * S_CAP + lane];
        float acc[8] = {0, 0, 0, 0, 0, 0, 0, 0};
        for (int gg = 0; gg < lim; gg += 16) {
            int k = gg + slot;
            int src = __shfl(idxv, k);
            bool ok = k < lim;
            ush8 v = *(const ush8*)(gbuf + (size_t)(ok ? src : i) * OUT_CH + chunk * 8);
#pragma unroll
            for (int j = 0; j < 8; ++j) acc[j] += ok ? bf2f(v[j]) : 0.0f;
        }
        if (dg > S_CAP) {   // wave-uniform; ~never taken on bench data
            int on = min(*ovfn, OVF_CAP);
            for (int k = 0; k < on; ++k) {
                int2 pr = ((const int2*)ovf)[k];
                if (pr.x == i && slot == 0) {
                    ush8 v = *(const ush8*)(gbuf + (size_t)pr.y * OUT_CH + chunk * 8);
#pragma unroll
                    for (int j = 0; j < 8; ++j) acc[j] += bf2f(v[j]);
                }
            }
        }
#pragma unroll
        for (int j = 0; j < 8; ++j) {
            acc[j] += __shfl_xor(acc[j], 4);
            acc[j] += __shfl_xor(acc[j], 8);
            acc[j] += __shfl_xor(acc[j], 16);
            acc[j] += __shfl_xor(acc[j], 32);
        }
        if (slot == 0) {   // lanes 0..3 hold chunk 0..3
            float rdeg = 1.0f / (float)(dg > 1 ? dg : 1);
            ush8 selfv = *(const ush8*)(hs + (size_t)i * HID + 32 + chunk * 8);
            if (fb) {
                ush8 ov;
#pragma unroll
                for (int j = 0; j < 8; ++j)
                    ov[j] = f2bf(acc[j] * rdeg + bf2f(selfv[j]));
                *(ush8*)((ush*)out + (size_t)i * OUT_CH + chunk * 8) = ov;
            } else {
                float* op = (float*)out + (size_t)i * OUT_CH + chunk * 8;
                f4 a0, a1;
#pragma unroll
                for (int j = 0; j < 4; ++j) {
                    a0[j] = acc[j] * rdeg + bf2f(selfv[j]);
                    a1[j] = acc[4 + j] * rdeg + bf2f(selfv[4 + j]);
                }
                *(f4*)op = a0;
                *(f4*)(op + 4) = a1;
            }
        }
    }
}

extern "C" void kernel_launch(void* const* d_in, const int* in_sizes, int n_in,
                              void* d_out, int out_size, void* d_ws, size_t ws_size,
                              hipStream_t stream) {
    const void* x   = d_in[0];
    const int*  ei  = (const int*)d_in[1];
    const void* W1l = d_in[2];
    const void* W1r = d_in[3];
    const void* b1  = d_in[4];
    const void* W2l = d_in[5];
    const void* W2r = d_in[6];
    const void* b2  = d_in[7];

    int n_nodes = in_sizes[0] / IN_CH;
    int n_edges = in_sizes[1] / 2;

    // ws layout (~46 MB):
    //   [0,256)   flags (2 ints) + ovfn counter (at +128)
    //   cnt (N ints) | csr (N*S_CAP + 64 ints) | ovf (2*OVF_CAP ints)
    //   | h (N*HID bf16; after k_g, row = [h(32 stale) | s(32) | unused])
    //   | gbuf (N*OUT_CH bf16 dense — layer-2 gather source)
    char* ws = (char*)d_ws;
    size_t o_cnt = 256;
    size_t o_csr = (o_cnt + (size_t)n_nodes * 4 + 127) & ~(size_t)127;
    size_t o_ovf = (o_csr + ((size_t)n_nodes * S_CAP + 64) * 4 + 127) & ~(size_t)127;
    size_t o_h   = (o_ovf + (size_t)OVF_CAP * 8 + 255) & ~(size_t)255;
    size_t o_gb  = (o_h + (size_t)n_nodes * HID * 2 + 255) & ~(size_t)255;

    int* flags = (int*)ws;
    int* ovfn  = (int*)(ws + 128);
    int* cnt   = (int*)(ws + o_cnt);
    int* csr   = (int*)(ws + o_csr);
    int* ovf   = (int*)(ws + o_ovf);
    ush* h     = (ush*)(ws + o_h);
    ush* gbuf  = (ush*)(ws + o_gb);

    hipMemsetAsync(ws, 0, 256, stream);                          // flags + ovfn
    hipMemsetAsync(cnt, 0, (size_t)n_nodes * 4, stream);

    k_detect<<<1, 256, 0, stream>>>((const unsigned short*)x, ei, flags);
    k_fillp<<<(n_edges + 255) / 256, 256, 0, stream>>>(ei, n_edges, flags, cnt, csr, ovf, ovfn);

    // grid 2048 = 8 blocks/CU on 256 CUs -> 32 waves/CU residency (LDS 16KB allows 10)
    k_l1<<<2048, 256, 0, stream>>>(x, cnt, csr, ovf, ovfn, W1l, W1r, b1, flags, h, n_nodes);
    k_g<<<2048, 256, 0, stream>>>(h, gbuf, W2l, W2r, b2, flags, n_nodes);
    k_l2g<<<2048, 256, 0, stream>>>(gbuf, h, cnt, csr, ovf, ovfn, flags, d_out, n_nodes);
}

// Round 3
// 468.976 us; speedup vs baseline: 1.0739x; 1.0739x over previous
//
#include <hip/hip_runtime.h>
#include <hip/hip_bf16.h>

typedef __hip_bfloat16 bf16;
typedef unsigned short ush;
typedef __attribute__((ext_vector_type(8))) unsigned short ush8;
typedef __attribute__((ext_vector_type(4))) float f4;

#define IN_CH 32
#define HID 128
#define OUT_CH 32
#define S_CAP 32             // fixed csr slots per node; rank>=S_CAP -> overflow list
#define OVF_CAP 100000       // overflow pair capacity (bench data: ~0 used)

__device__ __forceinline__ float bf2f(ush u) {
    return __uint_as_float(((unsigned)u) << 16);
}
__device__ __forceinline__ ush f2bf(float f) {
    __hip_bfloat16 b = __float2bfloat16(f);
    return __builtin_bit_cast(ush, b);
}
__device__ __forceinline__ float ldf(const void* __restrict__ p, size_t idx, int isbf16) {
    return isbf16 ? bf2f(((const ush*)p)[idx]) : ((const float*)p)[idx];
}
__device__ __forceinline__ int ld_edge(const int* __restrict__ ei, size_t elem, int wide) {
    return wide ? ei[2 * elem] : ei[elem];
}

// ---------- sniff dtypes: flags[0]=float_is_bf16, flags[1]=edge_is_i64 ----------
__global__ void k_detect(const unsigned short* __restrict__ xraw,
                         const int* __restrict__ ei, int* __restrict__ flags) {
    __shared__ int cnt_exp, any_nz;
    if (threadIdx.x == 0) { cnt_exp = 0; any_nz = 0; }
    __syncthreads();
    int local = 0;
    for (int k = threadIdx.x; k < 4096; k += 256) {
        int e = (xraw[k] >> 7) & 0xFF;
        if (e >= 100 && e <= 140) ++local;
    }
    atomicAdd(&cnt_exp, local);
    for (int k = threadIdx.x; k < 2048; k += 256)
        if (ei[2 * k + 1] != 0) any_nz = 1;   // benign race
    __syncthreads();
    if (threadIdx.x == 0) {
        flags[0] = (cnt_exp > 3500) ? 1 : 0;
        flags[1] = any_nz ? 0 : 1;
    }
}

// ---------- fused count+place: ONE atomic per edge ----------
__global__ void k_fillp(const int* __restrict__ ei, int n_edges,
                        const int* __restrict__ flags,
                        int* __restrict__ cnt, int* __restrict__ csr,
                        int* __restrict__ ovf, int* __restrict__ ovfn) {
    int e = blockIdx.x * blockDim.x + threadIdx.x;
    if (e >= n_edges) return;
    int w = flags[1];
    int d  = ld_edge(ei, (size_t)n_edges + e, w);
    int sc = ld_edge(ei, (size_t)e, w);
    int r = atomicAdd(&cnt[d], 1);
    if (r < S_CAP) {
        csr[d * S_CAP + r] = sc;
    } else {
        int o = atomicAdd(ovfn, 1);
        if (o < OVF_CAP) { ((int2*)ovf)[o] = make_int2(d, sc); }
    }
}

// ==== k_agg1: agg[i][0..31] = mean_j x[j] — gather only, DUAL-node per wave ====
// lane = (slot 0..15 = edge slot, chunk 0..3 = 8-channel chunk); nodes (i, i+1) per wave
// __launch_bounds__(256,8): force VGPR<=64 -> 32 waves/CU (gather is latency-bound)
// agg stored f32 (aggf) if workspace allows, else bf16 (aggb, aliases gbuf region)
__global__ __launch_bounds__(256, 8) void k_agg1(
        const void* __restrict__ x,
        const int* __restrict__ cnt, const int* __restrict__ csr,
        const int* __restrict__ ovf, const int* __restrict__ ovfn,
        const int* __restrict__ flags,
        float* __restrict__ aggf, ush* __restrict__ aggb, int aggf32,
        int n_nodes) {
    int fb = flags[0];
    int t = threadIdx.x;
    int wave = t >> 6, lane = t & 63;
    int slot = lane >> 2;    // 0..15
    int chunk = lane & 3;    // 0..3
    int st = gridDim.x * 4 * 2;
    int i = (blockIdx.x * 4 + wave) * 2;
    if (i >= n_nodes) return;
    // prefetched csr row pair (64 ints = slots of node i and i+1) + degree pair
    int idxv = csr[(size_t)i * S_CAP + lane];
    int dgv  = cnt[min(i + (lane & 1), n_nodes - 1)];
    while (i < n_nodes) {
        int inext = i + st;
        int idxv_n = 0, dgv_n = 0;
        if (inext < n_nodes) {            // prefetch next pair (hides csr/cnt latency)
            idxv_n = csr[(size_t)inext * S_CAP + lane];
            dgv_n  = cnt[min(inext + (lane & 1), n_nodes - 1)];
        }
        int dg0 = __shfl(dgv, 0);
        int dg1 = __shfl(dgv, 1);
        bool has1 = (i + 1) < n_nodes;
        int lim0 = min(dg0, S_CAP);
        int lim1 = has1 ? min(dg1, S_CAP) : 0;
        int lmax = max(lim0, lim1);
        float acc0[8] = {0, 0, 0, 0, 0, 0, 0, 0};
        float acc1[8] = {0, 0, 0, 0, 0, 0, 0, 0};
        if (fb) {
            const ush* xb = (const ush*)x;
            for (int g = 0; g < lmax; g += 16) {
                int k = g + slot;
                int s0 = __shfl(idxv, k);
                int s1 = __shfl(idxv, 32 + k);
                bool ok0 = k < lim0;
                bool ok1 = k < lim1;
                ush8 v0 = *(const ush8*)(xb + (size_t)(ok0 ? s0 : i) * IN_CH + chunk * 8);
                ush8 v1 = *(const ush8*)(xb + (size_t)(ok1 ? s1 : i) * IN_CH + chunk * 8);
#pragma unroll
                for (int j = 0; j < 8; ++j) {
                    acc0[j] += ok0 ? bf2f(v0[j]) : 0.0f;
                    acc1[j] += ok1 ? bf2f(v1[j]) : 0.0f;
                }
            }
            if (dg0 > S_CAP) {   // wave-uniform; ~never taken
                int on = min(*ovfn, OVF_CAP);
                for (int k = 0; k < on; ++k) {
                    int2 pr = ((const int2*)ovf)[k];
                    if (pr.x == i && slot == 0) {
                        ush8 v = *(const ush8*)(xb + (size_t)pr.y * IN_CH + chunk * 8);
#pragma unroll
                        for (int j = 0; j < 8; ++j) acc0[j] += bf2f(v[j]);
                    }
                }
            }
            if (has1 && dg1 > S_CAP) {
                int on = min(*ovfn, OVF_CAP);
                for (int k = 0; k < on; ++k) {
                    int2 pr = ((const int2*)ovf)[k];
                    if (pr.x == i + 1 && slot == 0) {
                        ush8 v = *(const ush8*)(xb + (size_t)pr.y * IN_CH + chunk * 8);
#pragma unroll
                        for (int j = 0; j < 8; ++j) acc1[j] += bf2f(v[j]);
                    }
                }
            }
        } else {
            const float* xb = (const float*)x;
            for (int g = 0; g < lmax; g += 16) {
                int k = g + slot;
                int s0 = __shfl(idxv, k);
                int s1 = __shfl(idxv, 32 + k);
                bool ok0 = k < lim0;
                bool ok1 = k < lim1;
                const float* r0 = xb + (size_t)(ok0 ? s0 : i) * IN_CH + chunk * 8;
                const float* r1 = xb + (size_t)(ok1 ? s1 : i) * IN_CH + chunk * 8;
                f4 a0 = *(const f4*)r0;
                f4 a1 = *(const f4*)(r0 + 4);
                f4 b0 = *(const f4*)r1;
                f4 b1 = *(const f4*)(r1 + 4);
#pragma unroll
                for (int j = 0; j < 4; ++j) {
                    acc0[j]     += ok0 ? a0[j] : 0.0f;
                    acc0[4 + j] += ok0 ? a1[j] : 0.0f;
                    acc1[j]     += ok1 ? b0[j] : 0.0f;
                    acc1[4 + j] += ok1 ? b1[j] : 0.0f;
                }
            }
            if (dg0 > S_CAP) {
                int on = min(*ovfn, OVF_CAP);
                for (int k = 0; k < on; ++k) {
                    int2 pr = ((const int2*)ovf)[k];
                    if (pr.x == i && slot == 0) {
                        const float* rp = xb + (size_t)pr.y * IN_CH + chunk * 8;
                        f4 a0 = *(const f4*)rp;
                        f4 a1 = *(const f4*)(rp + 4);
#pragma unroll
                        for (int j = 0; j < 4; ++j) { acc0[j] += a0[j]; acc0[4 + j] += a1[j]; }
                    }
                }
            }
            if (has1 && dg1 > S_CAP) {
                int on = min(*ovfn, OVF_CAP);
                for (int k = 0; k < on; ++k) {
                    int2 pr = ((const int2*)ovf)[k];
                    if (pr.x == i + 1 && slot == 0) {
                        const float* rp = xb + (size_t)pr.y * IN_CH + chunk * 8;
                        f4 a0 = *(const f4*)rp;
                        f4 a1 = *(const f4*)(rp + 4);
#pragma unroll
                        for (int j = 0; j < 4; ++j) { acc1[j] += a0[j]; acc1[4 + j] += a1[j]; }
                    }
                }
            }
        }
#pragma unroll
        for (int j = 0; j < 8; ++j) {
            acc0[j] += __shfl_xor(acc0[j], 4);
            acc0[j] += __shfl_xor(acc0[j], 8);
            acc0[j] += __shfl_xor(acc0[j], 16);
            acc0[j] += __shfl_xor(acc0[j], 32);
            acc1[j] += __shfl_xor(acc1[j], 4);
            acc1[j] += __shfl_xor(acc1[j], 8);
            acc1[j] += __shfl_xor(acc1[j], 16);
            acc1[j] += __shfl_xor(acc1[j], 32);
        }
        if (lane < 8) {   // lanes 0..3: node i chunks 0..3; lanes 4..7: node i+1
            bool second = lane >= 4;
            if (!second || has1) {
                int node = second ? i + 1 : i;
                int dg = second ? dg1 : dg0;
                float rd = 1.0f / (float)(dg > 1 ? dg : 1);
                int c = lane & 3;
                float o[8];
#pragma unroll
                for (int j = 0; j < 8; ++j)
                    o[j] = (second ? acc1[j] : acc0[j]) * rd;
                if (aggf32) {
                    float* op = aggf + (size_t)node * IN_CH + c * 8;
                    f4 o0, o1;
#pragma unroll
                    for (int j = 0; j < 4; ++j) { o0[j] = o[j]; o1[j] = o[4 + j]; }
                    *(f4*)op = o0;
                    *(f4*)(op + 4) = o1;
                } else {
                    ush8 ov;
#pragma unroll
                    for (int j = 0; j < 8; ++j) ov[j] = f2bf(o[j]);
                    *(ush8*)(aggb + (size_t)node * IN_CH + c * 8) = ov;
                }
            }
        }
        i = inext; idxv = idxv_n; dgv = dgv_n;
    }
}

// ==== k_mm1: h[i] = relu(agg[i]@W1l^T + x[i]@W1r^T + b1), dense streaming ====
// wave-per-node; lane = (slot 0..15 = 8-output group, chunk 0..3 = 8-ch chunk)
__global__ __launch_bounds__(256) void k_mm1(
        const void* __restrict__ x,
        const float* __restrict__ aggf, const ush* __restrict__ aggb, int aggf32,
        const void* __restrict__ W1l, const void* __restrict__ W1r,
        const void* __restrict__ b1,
        const int* __restrict__ flags,
        ush* __restrict__ hout, int n_nodes) {
    __shared__ ush wst[2 * HID * IN_CH];   // 16 KB: W1l then W1r, bf16 [o][c]
    int fb = flags[0];
    int t = threadIdx.x;
    for (int idx = t; idx < HID * IN_CH; idx += 256) {
        wst[idx]                 = f2bf(ldf(W1l, idx, fb));
        wst[HID * IN_CH + idx]   = f2bf(ldf(W1r, idx, fb));
    }
    __syncthreads();
    int wave = t >> 6, lane = t & 63;
    int slot = lane >> 2;    // 0..15
    int chunk = lane & 3;    // 0..3
    ush8 wlr[8], wrr[8];
    float bsr[8];
#pragma unroll
    for (int j = 0; j < 8; ++j) {
        int o = slot * 8 + j;
        wlr[j] = *(const ush8*)&wst[o * IN_CH + chunk * 8];
        wrr[j] = *(const ush8*)&wst[HID * IN_CH + o * IN_CH + chunk * 8];
        bsr[j] = ldf(b1, o, fb);
    }
    int gw = blockIdx.x * 4 + wave;
    int nw = gridDim.x * 4;
    for (int i = gw; i < n_nodes; i += nw) {
        float acc[8], sv[8];
        if (aggf32) {
            const float* ap = aggf + (size_t)i * IN_CH + chunk * 8;
            f4 g0 = *(const f4*)ap;
            f4 g1 = *(const f4*)(ap + 4);
#pragma unroll
            for (int j = 0; j < 4; ++j) { acc[j] = g0[j]; acc[4 + j] = g1[j]; }
        } else {
            ush8 av = *(const ush8*)(aggb + (size_t)i * IN_CH + chunk * 8);
#pragma unroll
            for (int j = 0; j < 8; ++j) acc[j] = bf2f(av[j]);
        }
        if (fb) {
            ush8 svv = *(const ush8*)((const ush*)x + (size_t)i * IN_CH + chunk * 8);
#pragma unroll
            for (int j = 0; j < 8; ++j) sv[j] = bf2f(svv[j]);
        } else {
            const float* rp = (const float*)x + (size_t)i * IN_CH + chunk * 8;
            f4 a0 = *(const f4*)rp;
            f4 a1 = *(const f4*)(rp + 4);
#pragma unroll
            for (int j = 0; j < 4; ++j) { sv[j] = a0[j]; sv[4 + j] = a1[j]; }
        }
        float po[8];
#pragma unroll
        for (int j = 0; j < 8; ++j) {
            float s = 0.0f;
#pragma unroll
            for (int c = 0; c < 8; ++c)
                s += acc[c] * bf2f(wlr[j][c]) + sv[c] * bf2f(wrr[j][c]);
            po[j] = s;
        }
#pragma unroll
        for (int j = 0; j < 8; ++j) {
            po[j] += __shfl_xor(po[j], 1);
            po[j] += __shfl_xor(po[j], 2);
        }
        if (chunk == 0) {
            ush8 ov;
#pragma unroll
            for (int j = 0; j < 8; ++j) {
                float v = po[j] + bsr[j];
                ov[j] = f2bf(v > 0.0f ? v : 0.0f);
            }
            *(ush8*)(hout + (size_t)i * HID + slot * 8) = ov;
        }
    }
}

// ==== k_g: g -> DENSE gbuf[N][32]; s -> h row [32..63] ====
__global__ __launch_bounds__(256) void k_g(
        ush* __restrict__ h, ush* __restrict__ gout,
        const void* __restrict__ W2l, const void* __restrict__ W2r,
        const void* __restrict__ b2,
        const int* __restrict__ flags, int n_nodes) {
    __shared__ ush wst[2 * OUT_CH * HID];  // 16 KB
    int fb = flags[0];
    int t = threadIdx.x;
    for (int idx = t; idx < OUT_CH * HID; idx += 256) {
        wst[idx]                  = f2bf(ldf(W2l, idx, fb));
        wst[OUT_CH * HID + idx]   = f2bf(ldf(W2r, idx, fb));
    }
    __syncthreads();
    int wave = t >> 6, lane = t & 63;
    int slot = lane >> 4;    // 0..3
    int chunk = lane & 15;   // 0..15
    ush8 wlr[8], wrr[8];
    float bsr[8];
#pragma unroll
    for (int j = 0; j < 8; ++j) {
        int o = slot * 8 + j;
        wlr[j] = *(const ush8*)&wst[o * HID + chunk * 8];
        wrr[j] = *(const ush8*)&wst[OUT_CH * HID + o * HID + chunk * 8];
        bsr[j] = ldf(b2, o, fb);
    }
    int gw = blockIdx.x * 4 + wave;
    int nw = gridDim.x * 4;
    for (int i = gw; i < n_nodes; i += nw) {
        ush8 hv = *(const ush8*)(h + (size_t)i * HID + chunk * 8);  // read BEFORE write
        float sv[8];
#pragma unroll
        for (int j = 0; j < 8; ++j) sv[j] = bf2f(hv[j]);
        float pg[8], ps[8];
#pragma unroll
        for (int j = 0; j < 8; ++j) {
            float a = 0.0f, b = 0.0f;
#pragma unroll
            for (int c = 0; c < 8; ++c) {
                a += sv[c] * bf2f(wlr[j][c]);
                b += sv[c] * bf2f(wrr[j][c]);
            }
            pg[j] = a; ps[j] = b;
        }
#pragma unroll
        for (int j = 0; j < 8; ++j) {
            pg[j] += __shfl_xor(pg[j], 1);
            pg[j] += __shfl_xor(pg[j], 2);
            pg[j] += __shfl_xor(pg[j], 4);
            pg[j] += __shfl_xor(pg[j], 8);
            ps[j] += __shfl_xor(ps[j], 1);
            ps[j] += __shfl_xor(ps[j], 2);
            ps[j] += __shfl_xor(ps[j], 4);
            ps[j] += __shfl_xor(ps[j], 8);
        }
        if (chunk == 0) {
            ush8 go, so;
#pragma unroll
            for (int j = 0; j < 8; ++j) {
                go[j] = f2bf(pg[j]);
                so[j] = f2bf(ps[j] + bsr[j]);
            }
            *(ush8*)(gout + (size_t)i * OUT_CH + slot * 8)    = go;   // g -> dense [N][32]
            *(ush8*)(h + (size_t)i * HID + 32 + slot * 8)     = so;   // s -> h row [32..63]
        }
    }
}

// ==== k_l2g: out[i] = mean_j g[j] + s[i] — DUAL-node gather from dense gbuf ====
__global__ __launch_bounds__(256, 8) void k_l2g(
        const ush* __restrict__ gbuf, const ush* __restrict__ hs,
        const int* __restrict__ cnt, const int* __restrict__ csr,
        const int* __restrict__ ovf, const int* __restrict__ ovfn,
        const int* __restrict__ flags,
        void* __restrict__ out, int n_nodes) {
    int fb = flags[0];
    int t = threadIdx.x;
    int wave = t >> 6, lane = t & 63;
    int slot = lane >> 2;    // 0..15
    int chunk = lane & 3;    // 0..3
    int st = gridDim.x * 4 * 2;
    int i = (blockIdx.x * 4 + wave) * 2;
    if (i >= n_nodes) return;
    int idxv = csr[(size_t)i * S_CAP + lane];
    int dgv  = cnt[min(i + (lane & 1), n_nodes - 1)];
    while (i < n_nodes) {
        int inext = i + st;
        int idxv_n = 0, dgv_n = 0;
        if (inext < n_nodes) {
            idxv_n = csr[(size_t)inext * S_CAP + lane];
            dgv_n  = cnt[min(inext + (lane & 1), n_nodes - 1)];
        }
        int dg0 = __shfl(dgv, 0);
        int dg1 = __shfl(dgv, 1);
        bool has1 = (i + 1) < n_nodes;
        int lim0 = min(dg0, S_CAP);
        int lim1 = has1 ? min(dg1, S_CAP) : 0;
        int lmax = max(lim0, lim1);
        float acc0[8] = {0, 0, 0, 0, 0, 0, 0, 0};
        float acc1[8] = {0, 0, 0, 0, 0, 0, 0, 0};
        for (int g = 0; g < lmax; g += 16) {
            int k = g + slot;
            int s0 = __shfl(idxv, k);
            int s1 = __shfl(idxv, 32 + k);
            bool ok0 = k < lim0;
            bool ok1 = k < lim1;
            ush8 v0 = *(const ush8*)(gbuf + (size_t)(ok0 ? s0 : i) * OUT_CH + chunk * 8);
            ush8 v1 = *(const ush8*)(gbuf + (size_t)(ok1 ? s1 : i) * OUT_CH + chunk * 8);
#pragma unroll
            for (int j = 0; j < 8; ++j) {
                acc0[j] += ok0 ? bf2f(v0[j]) : 0.0f;
                acc1[j] += ok1 ? bf2f(v1[j]) : 0.0f;
            }
        }
        if (dg0 > S_CAP) {   // wave-uniform; ~never taken
            int on = min(*ovfn, OVF_CAP);
            for (int k = 0; k < on; ++k) {
                int2 pr = ((const int2*)ovf)[k];
                if (pr.x == i && slot == 0) {
                    ush8 v = *(const ush8*)(gbuf + (size_t)pr.y * OUT_CH + chunk * 8);
#pragma unroll
                    for (int j = 0; j < 8; ++j) acc0[j] += bf2f(v[j]);
                }
            }
        }
        if (has1 && dg1 > S_CAP) {
            int on = min(*ovfn, OVF_CAP);
            for (int k = 0; k < on; ++k) {
                int2 pr = ((const int2*)ovf)[k];
                if (pr.x == i + 1 && slot == 0) {
                    ush8 v = *(const ush8*)(gbuf + (size_t)pr.y * OUT_CH + chunk * 8);
#pragma unroll
                    for (int j = 0; j < 8; ++j) acc1[j] += bf2f(v[j]);
                }
            }
        }
#pragma unroll
        for (int j = 0; j < 8; ++j) {
            acc0[j] += __shfl_xor(acc0[j], 4);
            acc0[j] += __shfl_xor(acc0[j], 8);
            acc0[j] += __shfl_xor(acc0[j], 16);
            acc0[j] += __shfl_xor(acc0[j], 32);
            acc1[j] += __shfl_xor(acc1[j], 4);
            acc1[j] += __shfl_xor(acc1[j], 8);
            acc1[j] += __shfl_xor(acc1[j], 16);
            acc1[j] += __shfl_xor(acc1[j], 32);
        }
        if (lane < 8) {   // lanes 0..3: node i; lanes 4..7: node i+1
            bool second = lane >= 4;
            if (!second || has1) {
                int node = second ? i + 1 : i;
                int dg = second ? dg1 : dg0;
                float rd = 1.0f / (float)(dg > 1 ? dg : 1);
                int c = lane & 3;
                ush8 selfv = *(const ush8*)(hs + (size_t)node * HID + 32 + c * 8);
                if (fb) {
                    ush8 ov;
#pragma unroll
                    for (int j = 0; j < 8; ++j) {
                        float a = second ? acc1[j] : acc0[j];
                        ov[j] = f2bf(a * rd + bf2f(selfv[j]));
                    }
                    *(ush8*)((ush*)out + (size_t)node * OUT_CH + c * 8) = ov;
                } else {
                    float* op = (float*)out + (size_t)node * OUT_CH + c * 8;
                    f4 a0, a1;
#pragma unroll
                    for (int j = 0; j < 4; ++j) {
                        float x0 = second ? acc1[j]     : acc0[j];
                        float x1 = second ? acc1[4 + j] : acc0[4 + j];
                        a0[j] = x0 * rd + bf2f(selfv[j]);
                        a1[j] = x1 * rd + bf2f(selfv[4 + j]);
                    }
                    *(f4*)op = a0;
                    *(f4*)(op + 4) = a1;
                }
            }
        }
        i = inext; idxv = idxv_n; dgv = dgv_n;
    }
}

extern "C" void kernel_launch(void* const* d_in, const int* in_sizes, int n_in,
                              void* d_out, int out_size, void* d_ws, size_t ws_size,
                              hipStream_t stream) {
    const void* x   = d_in[0];
    const int*  ei  = (const int*)d_in[1];
    const void* W1l = d_in[2];
    const void* W1r = d_in[3];
    const void* b1  = d_in[4];
    const void* W2l = d_in[5];
    const void* W2r = d_in[6];
    const void* b2  = d_in[7];

    int n_nodes = in_sizes[0] / IN_CH;
    int n_edges = in_sizes[1] / 2;

    // ws layout:
    //   [0,256)   flags (2 ints) + ovfn counter (at +128)
    //   cnt (N ints) | csr (N*S_CAP + 64 ints) | ovf (2*OVF_CAP ints)
    //   | h (N*HID bf16) | gbuf (N*OUT_CH bf16)
    //   | agg (N*IN_CH f32)  -- ONLY if ws_size permits; else agg is stored
    //     bf16 aliased onto gbuf (dead until k_g, which runs after k_mm1)
    char* ws = (char*)d_ws;
    size_t o_cnt = 256;
    size_t o_csr = (o_cnt + (size_t)n_nodes * 4 + 127) & ~(size_t)127;
    size_t o_ovf = (o_csr + ((size_t)n_nodes * S_CAP + 64) * 4 + 127) & ~(size_t)127;
    size_t o_h   = (o_ovf + (size_t)OVF_CAP * 8 + 255) & ~(size_t)255;
    size_t o_gb  = (o_h + (size_t)n_nodes * HID * 2 + 255) & ~(size_t)255;
    size_t o_ag  = (o_gb + (size_t)n_nodes * OUT_CH * 2 + 255) & ~(size_t)255;
    size_t need_f32 = o_ag + (size_t)n_nodes * IN_CH * 4;

    int* flags = (int*)ws;
    int* ovfn  = (int*)(ws + 128);
    int* cnt   = (int*)(ws + o_cnt);
    int* csr   = (int*)(ws + o_csr);
    int* ovf   = (int*)(ws + o_ovf);
    ush* h     = (ush*)(ws + o_h);
    ush* gbuf  = (ush*)(ws + o_gb);

    int aggf32 = (ws_size >= need_f32) ? 1 : 0;
    float* aggf = (float*)(ws + o_ag);   // valid only if aggf32
    ush*   aggb = gbuf;                  // bf16 fallback aliases gbuf (safe: dead by k_g)

    hipMemsetAsync(ws, 0, 256, stream);                          // flags + ovfn
    hipMemsetAsync(cnt, 0, (size_t)n_nodes * 4, stream);

    k_detect<<<1, 256, 0, stream>>>((const unsigned short*)x, ei, flags);
    k_fillp<<<(n_edges + 255) / 256, 256, 0, stream>>>(ei, n_edges, flags, cnt, csr, ovf, ovfn);

    // gather kernels: lean VGPR (<=64) -> 32 waves/CU; 2048 blocks = 8/CU residency cap
    k_agg1<<<2048, 256, 0, stream>>>(x, cnt, csr, ovf, ovfn, flags, aggf, aggb, aggf32, n_nodes);
    // dense kernels: ~104 VGPR -> 4 blocks/CU cap; 1024 blocks exactly fills it
    k_mm1<<<1024, 256, 0, stream>>>(x, aggf, aggb, aggf32, W1l, W1r, b1, flags, h, n_nodes);
    k_g<<<1024, 256, 0, stream>>>(h, gbuf, W2l, W2r, b2, flags, n_nodes);
    k_l2g<<<2048, 256, 0, stream>>>(gbuf, h, cnt, csr, ovf, ovfn, flags, d_out, n_nodes);
}